// Round 1
// baseline (236.441 us; speedup 1.0000x reference)
//
#include <hip/hip_runtime.h>
#include <hip/hip_bf16.h>

typedef __attribute__((ext_vector_type(8))) short short8;
typedef __attribute__((ext_vector_type(4))) float float4v;

#define MFMA16(a, b, c) __builtin_amdgcn_mfma_f32_16x16x32_bf16(a, b, c, 0, 0, 0)

__device__ __forceinline__ short f2bf(float f) {
    __hip_bfloat16 hb = __float2bfloat16(f);
    return *reinterpret_cast<short*>(&hb);
}

// ---------------------------------------------------------------------------
// Kernel 1: projection GEMM.  C[8192,1024] = A[8192,512] @ W[512,1024] + bias
// Epilogue scatters into Q[b][h][n][64] / K[b][h][n][64] bf16 (split at col 512).
// grid: (128 mtiles, 16 ctiles, 2 gemms), block 256 (4 waves), 64x64 tile.
// ---------------------------------------------------------------------------
__global__ __launch_bounds__(256) void proj_kernel(
    const float* __restrict__ nv, const float* __restrict__ rv,
    const float* __restrict__ Wn, const float* __restrict__ bn,
    const float* __restrict__ Wr, const float* __restrict__ br,
    __hip_bfloat16* __restrict__ Qn, __hip_bfloat16* __restrict__ Kn,
    __hip_bfloat16* __restrict__ Qr, __hip_bfloat16* __restrict__ Kr)
{
    const int m0 = blockIdx.x * 64;
    const int c0 = blockIdx.y * 64;
    const int g  = blockIdx.z;
    const float* A    = g ? rv : nv;
    const float* W    = g ? Wr : Wn;
    const float* bias = g ? br : bn;
    __hip_bfloat16* Qd = g ? Qr : Qn;
    __hip_bfloat16* Kd = g ? Kr : Kn;

    __shared__ short Bt[64][40];   // [col][k] bf16, padded row=40 shorts (80B)

    const int t    = threadIdx.x;
    const int lane = t & 63;
    const int w    = t >> 6;
    const int l15  = lane & 15;
    const int lg   = lane >> 4;     // 0..3
    const int kgrp = lg * 8;

    float4v acc[4] = {};
    const int mrow = m0 + w * 16 + l15;   // A-operand row for this lane

    for (int kk = 0; kk < 512; kk += 32) {
        // stage W tile transposed: Bt[c][k]
        {
            const int ci = t & 63;
            const int k0 = (t >> 6) * 8;
            #pragma unroll
            for (int ki = 0; ki < 8; ++ki) {
                float v = W[(kk + k0 + ki) * 1024 + c0 + ci];
                Bt[ci][k0 + ki] = f2bf(v);
            }
        }
        __syncthreads();
        // A fragment: 8 consecutive k at fixed row (contiguous f32)
        short8 afrag;
        {
            const float* ap = A + (size_t)mrow * 512 + kk + kgrp;
            float4 a0 = *reinterpret_cast<const float4*>(ap);
            float4 a1 = *reinterpret_cast<const float4*>(ap + 4);
            short* af = (short*)&afrag;
            af[0] = f2bf(a0.x); af[1] = f2bf(a0.y); af[2] = f2bf(a0.z); af[3] = f2bf(a0.w);
            af[4] = f2bf(a1.x); af[5] = f2bf(a1.y); af[6] = f2bf(a1.z); af[7] = f2bf(a1.w);
        }
        #pragma unroll
        for (int cs = 0; cs < 4; ++cs) {
            short8 bfrag = *reinterpret_cast<const short8*>(&Bt[cs * 16 + l15][kgrp]);
            acc[cs] = MFMA16(afrag, bfrag, acc[cs]);
        }
        __syncthreads();
    }

    // epilogue: bias + scatter to Q/K [b][h][n][64]
    const bool isK = (c0 >= 512);
    const int hh   = (c0 & 511) >> 6;
    __hip_bfloat16* dst = isK ? Kd : Qd;
    #pragma unroll
    for (int cs = 0; cs < 4; ++cs) {
        const int c  = c0 + cs * 16 + l15;
        const int d  = c & 63;
        const float bv = bias[c];
        #pragma unroll
        for (int r = 0; r < 4; ++r) {
            const int m = m0 + w * 16 + lg * 4 + r;   // C/D row mapping
            const int b = m >> 10, n = m & 1023;
            dst[(((size_t)(b * 8 + hh) * 1024 + n) * 64) + d] =
                __float2bfloat16(acc[cs][r] + bv);
        }
    }
}

// ---------------------------------------------------------------------------
// Kernel 2: V transpose.  nv/rv [b][n][512] f32  ->  Vt [b][h][d=64][n=1024] bf16
// grid: (32 = 16 ntiles x 2 srcs, 8 h, 8 b), block 256.
// ---------------------------------------------------------------------------
__global__ __launch_bounds__(256) void transpose_kernel(
    const float* __restrict__ nv, const float* __restrict__ rv,
    __hip_bfloat16* __restrict__ Vtn, __hip_bfloat16* __restrict__ Vtr)
{
    const int ntile = blockIdx.x & 15;
    const int src   = blockIdx.x >> 4;
    const int h     = blockIdx.y;
    const int b     = blockIdx.z;
    const float* V  = src ? rv : nv;
    __hip_bfloat16* Vt = src ? Vtr : Vtn;

    __shared__ short lds[64][72];   // [d][n], padded (144B rows, 16B-aligned)
    const int t  = threadIdx.x;
    const int n0 = ntile * 64;
    {
        const int i  = t >> 2;            // n within tile
        const int j0 = (t & 3) * 16;      // d chunk
        const float* p = V + ((size_t)(b * 1024) + n0 + i) * 512 + h * 64 + j0;
        #pragma unroll
        for (int jj = 0; jj < 16; ++jj)
            lds[j0 + jj][i] = f2bf(p[jj]);
    }
    __syncthreads();
    {
        const int j  = t >> 2;            // d row
        const int i0 = (t & 3) * 16;      // n chunk
        __hip_bfloat16* q = Vt + (((size_t)(b * 8 + h) * 64) + j) * 1024 + n0 + i0;
        short8 v0 = *reinterpret_cast<const short8*>(&lds[j][i0]);
        short8 v1 = *reinterpret_cast<const short8*>(&lds[j][i0 + 8]);
        *reinterpret_cast<short8*>(q)     = v0;
        *reinterpret_cast<short8*>(q + 8) = v1;
    }
}

// ---------------------------------------------------------------------------
// Kernel 3: attention with softmax over HEADS.
// grid: (32 ntiles of 32 rows, 8 b, 2 dirs), block 256 (4 waves).
// Wave w owns heads {2w, 2w+1}. Per m-tile(32): S (QK^T MFMA, frags direct
// from global) -> LDS; per-(n,m) softmax over 8 heads in-thread; P bf16 ->
// LDS; PV MFMA accumulate. SCALE folded into exp.
// ---------------------------------------------------------------------------
__global__ __launch_bounds__(256) void attn_kernel(
    const __hip_bfloat16* __restrict__ Qn, const __hip_bfloat16* __restrict__ Kn,
    const __hip_bfloat16* __restrict__ Qr, const __hip_bfloat16* __restrict__ Kr,
    const __hip_bfloat16* __restrict__ Vtn, const __hip_bfloat16* __restrict__ Vtr,
    float* __restrict__ out)
{
    const int ntile = blockIdx.x;     // 0..31
    const int b     = blockIdx.y;     // 0..7
    const int dir   = blockIdx.z;     // 0: noise out, 1: rgb out
    const __hip_bfloat16* Q  = dir ? Qr  : Qn;
    const __hip_bfloat16* K  = dir ? Kn  : Kr;
    const __hip_bfloat16* Vt = dir ? Vtn : Vtr;
    float* O = out + (size_t)dir * (8u * 1024u * 512u);

    const int t    = threadIdx.x;
    const int lane = t & 63;
    const int w    = t >> 6;          // wave 0..3
    const int l15  = lane & 15;
    const int lg   = lane >> 4;       // 0..3

    __shared__ float S_s[8][32][33];  // [h][n][m] f32, +1 pad
    __shared__ short P_s[8][32][40];  // [h][n][m] bf16, pad to 40 (80B rows)

    const int n0 = ntile * 32;

    // Q fragments held in registers: [head2][nsub][kfrag]
    short8 qf[2][2][2];
    #pragma unroll
    for (int hh = 0; hh < 2; ++hh) {
        const int h = w * 2 + hh;
        #pragma unroll
        for (int i = 0; i < 2; ++i)
            #pragma unroll
            for (int kc = 0; kc < 2; ++kc) {
                const __hip_bfloat16* qp =
                    Q + ((size_t)((b * 8 + h) * 1024) + n0 + i * 16 + l15) * 64 + kc * 32 + lg * 8;
                qf[hh][i][kc] = *reinterpret_cast<const short8*>(qp);
            }
    }

    float4v oacc[2][2][4] = {};       // [head2][nsub][dsub]

    for (int m0 = 0; m0 < 1024; m0 += 32) {
        // ---- S = Q K^T for owned heads ----
        #pragma unroll
        for (int hh = 0; hh < 2; ++hh) {
            const int h = w * 2 + hh;
            const __hip_bfloat16* Kb = K + (size_t)((b * 8 + h) * 1024) * 64;
            #pragma unroll
            for (int i = 0; i < 2; ++i) {
                #pragma unroll
                for (int j = 0; j < 2; ++j) {
                    float4v s = {};
                    #pragma unroll
                    for (int kc = 0; kc < 2; ++kc) {
                        short8 kf = *reinterpret_cast<const short8*>(
                            Kb + (size_t)(m0 + j * 16 + l15) * 64 + kc * 32 + lg * 8);
                        s = MFMA16(qf[hh][i][kc], kf, s);
                    }
                    #pragma unroll
                    for (int r = 0; r < 4; ++r)
                        S_s[h][i * 16 + lg * 4 + r][j * 16 + l15] = s[r];
                }
            }
        }
        __syncthreads();

        // ---- softmax over the 8 heads, per (n,m) position ----
        #pragma unroll
        for (int q = 0; q < 4; ++q) {
            const int pos = t + q * 256;
            const int n = pos >> 5;
            const int m = pos & 31;
            float sv[8];
            #pragma unroll
            for (int h = 0; h < 8; ++h) sv[h] = S_s[h][n][m];
            float mx = sv[0];
            #pragma unroll
            for (int h = 1; h < 8; ++h) mx = fmaxf(mx, sv[h]);
            float sum = 0.f;
            #pragma unroll
            for (int h = 0; h < 8; ++h) {
                sv[h] = __expf((sv[h] - mx) * 0.125f);   // SCALE folded in
                sum += sv[h];
            }
            const float inv = 1.0f / sum;
            #pragma unroll
            for (int h = 0; h < 8; ++h)
                P_s[h][n][m] = f2bf(sv[h] * inv);
        }
        __syncthreads();

        // ---- O += P V for owned heads ----
        #pragma unroll
        for (int hh = 0; hh < 2; ++hh) {
            const int h = w * 2 + hh;
            const __hip_bfloat16* Vb = Vt + (size_t)((b * 8 + h) * 64) * 1024;
            #pragma unroll
            for (int i = 0; i < 2; ++i) {
                short8 pf = *reinterpret_cast<const short8*>(&P_s[h][i * 16 + l15][lg * 8]);
                #pragma unroll
                for (int dd = 0; dd < 4; ++dd) {
                    short8 vf = *reinterpret_cast<const short8*>(
                        Vb + (size_t)(dd * 16 + l15) * 1024 + m0 + lg * 8);
                    oacc[hh][i][dd] = MFMA16(pf, vf, oacc[hh][i][dd]);
                }
            }
        }
        __syncthreads();
    }

    // ---- epilogue: O[b][n][h*64+d] f32 ----
    #pragma unroll
    for (int hh = 0; hh < 2; ++hh) {
        const int h = w * 2 + hh;
        #pragma unroll
        for (int i = 0; i < 2; ++i)
            #pragma unroll
            for (int dd = 0; dd < 4; ++dd)
                #pragma unroll
                for (int r = 0; r < 4; ++r) {
                    const int n = n0 + i * 16 + lg * 4 + r;
                    const int d = dd * 16 + l15;
                    O[((size_t)(b * 1024) + n) * 512 + h * 64 + d] = oacc[hh][i][dd][r];
                }
    }
}

extern "C" void kernel_launch(void* const* d_in, const int* in_sizes, int n_in,
                              void* d_out, int out_size, void* d_ws, size_t ws_size,
                              hipStream_t stream) {
    const float* nv = (const float*)d_in[0];
    const float* rv = (const float*)d_in[1];
    const float* Wn = (const float*)d_in[2];
    const float* bn = (const float*)d_in[3];
    const float* Wr = (const float*)d_in[4];
    const float* br = (const float*)d_in[5];
    float* out = (float*)d_out;

    __hip_bfloat16* w = (__hip_bfloat16*)d_ws;
    const size_t E = 8ull * 8 * 1024 * 64;   // 4M elems per tensor
    __hip_bfloat16* Qn  = w;
    __hip_bfloat16* Kn  = w + E;
    __hip_bfloat16* Qr  = w + 2 * E;
    __hip_bfloat16* Kr  = w + 3 * E;
    __hip_bfloat16* Vtn = w + 4 * E;
    __hip_bfloat16* Vtr = w + 5 * E;

    proj_kernel<<<dim3(128, 16, 2), 256, 0, stream>>>(nv, rv, Wn, bn, Wr, br, Qn, Kn, Qr, Kr);
    transpose_kernel<<<dim3(32, 8, 8), 256, 0, stream>>>(nv, rv, Vtn, Vtr);
    attn_kernel<<<dim3(32, 8, 2), 256, 0, stream>>>(Qn, Kn, Qr, Kr, Vtn, Vtr, out);
}